// Round 8
// baseline (160.837 us; speedup 1.0000x reference)
//
#include <hip/hip_runtime.h>
#include <cstddef>
#include <cstdint>

#define FN_ 100000
#define V_  50000
#define B_  8
#define NT  64
#define NBX ((FN_ + NT - 1) / NT)   // 1563; last bx has 32 valid cols
#define TT  (NBX * B_)              // 12504 column-tiles
#define GRIDX 1024                  // persistent-ish blocks, grid-stride over tiles
#define STR 448                     // f16 per column: 0..255 acts, 256..383 cv, 384..447 X dbuf

// d_ws layout (bytes): 48 weight tiles of 1 KB (fragment order), then shs f32[448]
//   tiles  0..15 : combined L1 weights (256x32): rows 0-63 c1, 64-127 e0, 128-191 e1, 192-255 e2
//   tiles 16..23 : c2 (64x64)   tile = 16 + 2*rt + s
//   tiles 24..31 : v2 (64x64, x1/3 folded)  tile = 24 + 2*rt + s
//   tiles 32..47 : s  (64x128)  tile = 32 + 4*rt + s
#define WS_SHS 49152

typedef _Float16 f16;
typedef f16   f16x8 __attribute__((ext_vector_type(8)));
typedef float f32x4 __attribute__((ext_vector_type(4)));

struct Ptrs { const void* p[33]; };

union Pk8 { f16 h[8]; uint4 u; };

// 2x f32 -> packed f16 (RTZ), as raw u32
__device__ __forceinline__ uint32_t pack2(float a, float b) {
  return __builtin_bit_cast(uint32_t, __builtin_amdgcn_cvt_pkrtz(a, b));
}
// packed relu on a u32 holding 2 f16
__device__ __forceinline__ uint32_t pack_relu2(float a, float b) {
  uint32_t r, x = pack2(a, b);
  asm("v_pk_max_f16 %0, %1, 0" : "=v"(r) : "v"(x));
  return r;
}

// ---------------- prep: fold BN into f16 weights, fragment-ordered (validated) ----------------
__global__ __launch_bounds__(1024) void sd_prep(Ptrs in, f16* __restrict__ wsW,
                                                float* __restrict__ shsG)
{
  const float* __restrict__ cw1 = (const float*)in.p[3];
  const float* __restrict__ cb1 = (const float*)in.p[4];
  const float* __restrict__ c1g = (const float*)in.p[5];
  const float* __restrict__ c1bt= (const float*)in.p[6];
  const float* __restrict__ c1m = (const float*)in.p[7];
  const float* __restrict__ c1v = (const float*)in.p[8];
  const float* __restrict__ cw2 = (const float*)in.p[9];
  const float* __restrict__ cb2 = (const float*)in.p[10];
  const float* __restrict__ c2g = (const float*)in.p[11];
  const float* __restrict__ c2bt= (const float*)in.p[12];
  const float* __restrict__ c2m = (const float*)in.p[13];
  const float* __restrict__ c2v = (const float*)in.p[14];
  const float* __restrict__ vw1 = (const float*)in.p[15];
  const float* __restrict__ vb1 = (const float*)in.p[16];
  const float* __restrict__ v1g = (const float*)in.p[17];
  const float* __restrict__ v1bt= (const float*)in.p[18];
  const float* __restrict__ v1m = (const float*)in.p[19];
  const float* __restrict__ v1v = (const float*)in.p[20];
  const float* __restrict__ vw2 = (const float*)in.p[21];
  const float* __restrict__ vb2 = (const float*)in.p[22];
  const float* __restrict__ v2g = (const float*)in.p[23];
  const float* __restrict__ v2bt= (const float*)in.p[24];
  const float* __restrict__ v2m = (const float*)in.p[25];
  const float* __restrict__ v2v = (const float*)in.p[26];
  const float* __restrict__ sw  = (const float*)in.p[27];
  const float* __restrict__ sb  = (const float*)in.p[28];
  const float* __restrict__ s1g = (const float*)in.p[29];
  const float* __restrict__ s1bt= (const float*)in.p[30];
  const float* __restrict__ s1m = (const float*)in.p[31];
  const float* __restrict__ s1v = (const float*)in.p[32];

  __shared__ float scsL[448];
  const int tid = threadIdx.x;

  if (tid < 448) {
    const float *g, *v, *bb, *m, *bt; int o; float mul = 1.f;
    if (tid < 64)       { o = tid;      g=c1g; v=c1v; bb=cb1; m=c1m; bt=c1bt; }
    else if (tid < 256) { o = tid & 63; g=v1g; v=v1v; bb=vb1; m=v1m; bt=v1bt; }
    else if (tid < 320) { o = tid-256;  g=c2g; v=c2v; bb=cb2; m=c2m; bt=c2bt; }
    else if (tid < 384) { o = tid-320;  g=v2g; v=v2v; bb=vb2; m=v2m; bt=v2bt; mul = 1.f/3.f; }
    else                { o = tid-384;  g=s1g; v=s1v; bb=sb;  m=s1m; bt=s1bt; }
    float s = g[o] * rsqrtf(v[o] + 1e-5f);
    scsL[tid] = s * mul;
    shsG[tid] = ((bb[o] - m[o]) * s + bt[o]) * mul;
  }
  __syncthreads();

  for (int u = tid; u < 3072; u += 1024) {
    const int t = u >> 6, l = u & 63, r15 = l & 15, g4 = l >> 4;
    Pk8 pk;
    if (t < 16) {                                   // L1 combined 256x32
      const int wm = t >> 2, tr = t & 3, row = 64*wm + 16*tr + r15;
#pragma unroll
      for (int j = 0; j < 8; ++j) {
        const int k = 8*g4 + j; float val = 0.f;
        if (wm == 0) { if (k >= 9 && k < 12) val = cw1[row*3 + (k-9)]; }
        else if (k < 9) {
          const int e = wm - 1, o = row - 64*wm, c = (k - 3*e + 9) % 9;
          if (c < 6) val = vw1[o*6 + c];
        }
        pk.h[j] = (f16)(val * scsL[row]);
      }
    } else if (t < 24) {                            // c2
      const int tt = t-16, rt = tt >> 1, s = tt & 1, row = 16*rt + r15;
#pragma unroll
      for (int j = 0; j < 8; ++j) { const int k = 32*s + 8*g4 + j;
        pk.h[j] = (f16)(cw2[row*64 + k] * scsL[256+row]); }
    } else if (t < 32) {                            // v2 (x 1/3)
      const int tt = t-24, rt = tt >> 1, s = tt & 1, row = 16*rt + r15;
#pragma unroll
      for (int j = 0; j < 8; ++j) { const int k = 32*s + 8*g4 + j;
        pk.h[j] = (f16)(vw2[row*64 + k] * scsL[320+row]); }
    } else {                                        // s (64x128)
      const int tt = t-32, rt = tt >> 2, s = tt & 3, row = 16*rt + r15;
#pragma unroll
      for (int j = 0; j < 8; ++j) { const int k = 32*s + 8*g4 + j;
        pk.h[j] = (f16)(sw[row*128 + k] * scsL[384+row]); }
    }
    *(uint4*)(wsW + (size_t)t*512 + l*8) = pk.u;
  }
}

// ---------------- main: persistent blocks, weights in regs, XOR-swizzled LDS ----------------
// Per tile (3 barriers): P2 {L2 + gather(next)} | P3 {cv write} | P4 {L3+stores + L1(next)}
__global__ __launch_bounds__(512, 4) void sd_main(const int* __restrict__ faces,
    const float* __restrict__ verts, const float* __restrict__ centers,
    const f16* __restrict__ wsW, const float* __restrict__ shsG,
    float* __restrict__ out)
{
  // flat, XOR-swizzled: addr = col*STR + (k ^ ((col&7)<<3)); all accesses use same map
  __shared__ __align__(16) f16 Hs[NT * STR];      // 57344 B -> 2 blocks/CU

  const int tid  = threadIdx.x;
  const int lane = tid & 63;
  const int r15  = lane & 15;
  const int g4   = lane >> 4;
  const int w    = __builtin_amdgcn_readfirstlane(tid >> 6);
  const int SW   = (r15 & 7) << 3;                // swizzle for col = 16*tc + r15
  const int rt   = w & 3, cg = w >> 2;            // L2/L3 tile position

  // ---- weights + shifts to registers, once per block ----
  const f16* wf = wsW + lane*8;
  const f16x8 wL1a = *(const f16x8*)(wf + (size_t)(2*w    )*512);
  const f16x8 wL1b = *(const f16x8*)(wf + (size_t)(2*w + 1)*512);
  const f16x8 wC2a = *(const f16x8*)(wf + (size_t)(16 + 2*rt    )*512);
  const f16x8 wC2b = *(const f16x8*)(wf + (size_t)(16 + 2*rt + 1)*512);
  const f16x8 wV2a = *(const f16x8*)(wf + (size_t)(24 + 2*rt    )*512);
  const f16x8 wV2b = *(const f16x8*)(wf + (size_t)(24 + 2*rt + 1)*512);
  f16x8 wS[4];
#pragma unroll
  for (int s = 0; s < 4; ++s)
    wS[s] = *(const f16x8*)(wf + (size_t)(32 + 4*rt + s)*512);
  const f32x4 shL1a = *(const f32x4*)&shsG[(2*w    )*16 + 4*g4];
  const f32x4 shL1b = *(const f32x4*)&shsG[(2*w + 1)*16 + 4*g4];
  const f32x4 shC2  = *(const f32x4*)&shsG[256 + rt*16 + 4*g4];
  const f32x4 shV2  = *(const f32x4*)&shsG[320 + rt*16 + 4*g4];
  const f32x4 shS   = *(const f32x4*)&shsG[384 + rt*16 + 4*g4];

  // ---- gather helper: 8 threads/col; writes X buf at logical k = xk..xk+11, swizzled ----
  auto gather = [&](int tile, int xk) {
    const int col = tid >> 3, p = tid & 7;
    const int by = tile / NBX, bx = tile - by*NBX;
    const int f = bx*NT + col;
    const bool valid = f < FN_;
    const int swg = (col & 7) << 3;
    f16* xp = &Hs[col*STR];
    if (p < 3) {
      float x0 = 0.f, x1 = 0.f, x2 = 0.f;
      if (valid) {
        const int vi = faces[((size_t)by*FN_ + f)*3 + p];
        const float* vp = verts + ((size_t)by*V_ + (size_t)vi)*3;
        x0 = vp[0]; x1 = vp[1]; x2 = vp[2];
      }
      const int k0 = xk + p*3;
      xp[(k0+0) ^ swg] = (f16)x0;
      xp[(k0+1) ^ swg] = (f16)x1;
      xp[(k0+2) ^ swg] = (f16)x2;
    } else if (p == 3) {
#pragma unroll
      for (int k = 0; k < 3; ++k)
        xp[(xk+9+k) ^ swg] = valid ? (f16)centers[((size_t)by*3 + k)*FN_ + f] : (f16)0.f;
    }
  };

  // ---- L1: W1[256x32] x X[32x64] -> acts k0..255; wave w owns row-tiles 2w,2w+1 ----
  auto runL1 = [&](int xk) {
    const int t0k = (2*w)*16 + 4*g4;
    const int t1k = t0k + 16;
#pragma unroll
    for (int tc = 0; tc < 4; ++tc) {
      const int colo = (16*tc + r15) * STR;
      const f16x8 b = *(const f16x8*)&Hs[colo + ((xk + 8*g4) ^ SW)];
      f32x4 c0 = __builtin_amdgcn_mfma_f32_16x16x32_f16(wL1a, b, shL1a, 0,0,0);
      f32x4 c1 = __builtin_amdgcn_mfma_f32_16x16x32_f16(wL1b, b, shL1b, 0,0,0);
      uint2 p0, p1;
      p0.x = pack_relu2(c0[0], c0[1]); p0.y = pack_relu2(c0[2], c0[3]);
      p1.x = pack_relu2(c1[0], c1[1]); p1.y = pack_relu2(c1[2], c1[3]);
      *(uint2*)&Hs[colo + (t0k ^ SW)] = p0;
      *(uint2*)&Hs[colo + (t1k ^ SW)] = p1;
    }
  };

  // ---- prologue: zero X pads (k12..31 both bufs), gather tile0, L1 ----
  {
    const int col = tid >> 3, p = tid & 7;
    const int swg = (col & 7) << 3;
    f16* xp = &Hs[col*STR];
#pragma unroll
    for (int z = 0; z < 5; ++z) {
      const int zz = p*5 + z;
      const int k = (zz < 20) ? (384 + 12 + zz) : (416 + 12 + (zz - 20));
      xp[k ^ swg] = (f16)0.f;
    }
  }
  int tile = blockIdx.x;
  gather(tile, 384);
  __syncthreads();
  runL1(384);
  __syncthreads();

  int cur = 0;
#pragma unroll 1
  for (;;) {
    const int nxt = tile + GRIDX;
    const bool hasNext = nxt < TT;
    const int xkNext = 384 + 32*(cur ^ 1);

    // ---- P2: L2 (4 branches, K=64) from acts; gather(next) overlapped ----
    float cf[2][4], vf[2][4];
#pragma unroll
    for (int br = 0; br < 4; ++br) {
      const f16x8 a0 = br ? wV2a : wC2a;
      const f16x8 a1 = br ? wV2b : wC2b;
      const f32x4 shv = br ? shV2 : shC2;
#pragma unroll
      for (int tc = 0; tc < 2; ++tc) {
        const int colo = (16*(2*cg + tc) + r15) * STR;
        const f16x8 b0 = *(const f16x8*)&Hs[colo + ((64*br +      8*g4) ^ SW)];
        const f16x8 b1 = *(const f16x8*)&Hs[colo + ((64*br + 32 + 8*g4) ^ SW)];
        f32x4 acc = __builtin_amdgcn_mfma_f32_16x16x32_f16(a0, b0, shv, 0,0,0);
        acc = __builtin_amdgcn_mfma_f32_16x16x32_f16(a1, b1, acc, 0,0,0);
#pragma unroll
        for (int j = 0; j < 4; ++j) {
          const float val = fmaxf(acc[j], 0.f);
          if (br == 0)      cf[tc][j]  = val;
          else if (br == 1) vf[tc][j]  = val;
          else              vf[tc][j] += val;
        }
      }
    }
    if (hasNext) gather(nxt, xkNext);
    __syncthreads();

    // ---- P3: cv write (cf -> k256..319, vf -> k320..383) ----
#pragma unroll
    for (int tc = 0; tc < 2; ++tc) {
      const int colo = (16*(2*cg + tc) + r15) * STR;
      const int o0 = rt*16 + 4*g4;
      uint2 pc, pv;
      pc.x = pack2(cf[tc][0], cf[tc][1]); pc.y = pack2(cf[tc][2], cf[tc][3]);
      pv.x = pack2(vf[tc][0], vf[tc][1]); pv.y = pack2(vf[tc][2], vf[tc][3]);
      *(uint2*)&Hs[colo + ((256 + o0) ^ SW)]      = pc;
      *(uint2*)&Hs[colo + ((256 + 64 + o0) ^ SW)] = pv;
    }
    __syncthreads();

    // ---- P4: L3 + stores(tile); L1(next) overlapped ----
    {
      f32x4 acc[2];
      acc[0] = shS; acc[1] = shS;
#pragma unroll
      for (int s = 0; s < 4; ++s) {
#pragma unroll
        for (int tc = 0; tc < 2; ++tc) {
          const int colo = (16*(2*cg + tc) + r15) * STR;
          const f16x8 b = *(const f16x8*)&Hs[colo + ((256 + 32*s + 8*g4) ^ SW)];
          acc[tc] = __builtin_amdgcn_mfma_f32_16x16x32_f16(wS[s], b, acc[tc], 0,0,0);
        }
      }
      const int by = tile / NBX, bx = tile - by*NBX;
      const int o0 = rt*16 + 4*g4;
#pragma unroll
      for (int tc = 0; tc < 2; ++tc) {
        const int f = bx*NT + 16*(2*cg + tc) + r15;
        if (f < FN_) {
          const size_t base = ((size_t)(by*64 + o0))*FN_ + (size_t)f;
#pragma unroll
          for (int j = 0; j < 4; ++j)
            out[base + (size_t)j*FN_] = fmaxf(acc[tc][j], 0.f);
        }
      }
    }
    if (!hasNext) break;
    runL1(xkNext);
    __syncthreads();
    tile = nxt; cur ^= 1;
  }
}

extern "C" void kernel_launch(void* const* d_in, const int* in_sizes, int n_in,
                              void* d_out, int out_size, void* d_ws, size_t ws_size,
                              hipStream_t stream) {
  (void)in_sizes; (void)n_in; (void)out_size; (void)ws_size;
  Ptrs p;
  for (int i = 0; i < 33; ++i) p.p[i] = d_in[i];
  f16*   wsW  = (f16*)d_ws;
  float* shsG = (float*)((char*)d_ws + WS_SHS);
  hipLaunchKernelGGL(sd_prep, dim3(1), dim3(1024), 0, stream, p, wsW, shsG);
  hipLaunchKernelGGL(sd_main, dim3(GRIDX), dim3(512), 0, stream,
                     (const int*)d_in[2], (const float*)d_in[1], (const float*)d_in[0],
                     wsW, shsG, (float*)d_out);
}

// Round 9
// 127.971 us; speedup vs baseline: 1.2568x; 1.2568x over previous
//
#include <hip/hip_runtime.h>
#include <cstddef>
#include <cstdint>

#define FN_ 100000
#define V_  50000
#define B_  8
// 100000 = 3125 * 32 -> each wave owns exactly 32 columns, no partial tiles.
#define WPB   8                     // waves per block (512 threads)
#define NBLK  3125                  // 25000 wave-tiles / 8

// d_ws layout (bytes): 48 weight tiles of 1 KB (fragment order), then shs f32[448]
//   tiles  0..15 : combined L1 (256x32): rows 0-63 c1, 64-127 e0, 128-191 e1, 192-255 e2
//                  k==12 column holds the folded BN SHIFT (bias-as-weight; X[12]=1)
//   tiles 16..23 : c2 (64x64)
//   tiles 24..31 : v2 (64x64, x1/3 folded)
//   tiles 32..47 : s  (64x128)   (read from global; L2-resident)
#define WS_SHS 49152

typedef _Float16 f16;
typedef f16   f16x8 __attribute__((ext_vector_type(8)));
typedef float f32x4 __attribute__((ext_vector_type(4)));

struct Ptrs { const void* p[33]; };

union Pk8 { f16 h[8]; uint4 u; };
union FragU { uint32_t u[4]; f16x8 v; };

__device__ __forceinline__ uint32_t pack2(float a, float b) {
  return __builtin_bit_cast(uint32_t, __builtin_amdgcn_cvt_pkrtz(a, b));
}
__device__ __forceinline__ uint32_t pack_relu2(float a, float b) {
  uint32_t r, x = pack2(a, b);
  asm("v_pk_max_f16 %0, %1, 0" : "=v"(r) : "v"(x));
  return r;
}

// ---------------- prep: fold BN into f16 weights, fragment-ordered ----------------
__global__ __launch_bounds__(1024) void sd_prep(Ptrs in, f16* __restrict__ wsW,
                                                float* __restrict__ shsG)
{
  const float* __restrict__ cw1 = (const float*)in.p[3];
  const float* __restrict__ cb1 = (const float*)in.p[4];
  const float* __restrict__ c1g = (const float*)in.p[5];
  const float* __restrict__ c1bt= (const float*)in.p[6];
  const float* __restrict__ c1m = (const float*)in.p[7];
  const float* __restrict__ c1v = (const float*)in.p[8];
  const float* __restrict__ cw2 = (const float*)in.p[9];
  const float* __restrict__ cb2 = (const float*)in.p[10];
  const float* __restrict__ c2g = (const float*)in.p[11];
  const float* __restrict__ c2bt= (const float*)in.p[12];
  const float* __restrict__ c2m = (const float*)in.p[13];
  const float* __restrict__ c2v = (const float*)in.p[14];
  const float* __restrict__ vw1 = (const float*)in.p[15];
  const float* __restrict__ vb1 = (const float*)in.p[16];
  const float* __restrict__ v1g = (const float*)in.p[17];
  const float* __restrict__ v1bt= (const float*)in.p[18];
  const float* __restrict__ v1m = (const float*)in.p[19];
  const float* __restrict__ v1v = (const float*)in.p[20];
  const float* __restrict__ vw2 = (const float*)in.p[21];
  const float* __restrict__ vb2 = (const float*)in.p[22];
  const float* __restrict__ v2g = (const float*)in.p[23];
  const float* __restrict__ v2bt= (const float*)in.p[24];
  const float* __restrict__ v2m = (const float*)in.p[25];
  const float* __restrict__ v2v = (const float*)in.p[26];
  const float* __restrict__ sw  = (const float*)in.p[27];
  const float* __restrict__ sb  = (const float*)in.p[28];
  const float* __restrict__ s1g = (const float*)in.p[29];
  const float* __restrict__ s1bt= (const float*)in.p[30];
  const float* __restrict__ s1m = (const float*)in.p[31];
  const float* __restrict__ s1v = (const float*)in.p[32];

  __shared__ float scsL[448];
  __shared__ float shfL[256];       // L1 shifts for the bias-column trick
  const int tid = threadIdx.x;

  if (tid < 448) {
    const float *g, *v, *bb, *m, *bt; int o; float mul = 1.f;
    if (tid < 64)       { o = tid;      g=c1g; v=c1v; bb=cb1; m=c1m; bt=c1bt; }
    else if (tid < 256) { o = tid & 63; g=v1g; v=v1v; bb=vb1; m=v1m; bt=v1bt; }
    else if (tid < 320) { o = tid-256;  g=c2g; v=c2v; bb=cb2; m=c2m; bt=c2bt; }
    else if (tid < 384) { o = tid-320;  g=v2g; v=v2v; bb=vb2; m=v2m; bt=v2bt; mul = 1.f/3.f; }
    else                { o = tid-384;  g=s1g; v=s1v; bb=sb;  m=s1m; bt=s1bt; }
    float s = g[o] * rsqrtf(v[o] + 1e-5f);
    float sh = ((bb[o] - m[o]) * s + bt[o]) * mul;
    scsL[tid] = s * mul;
    shsG[tid] = sh;
    if (tid < 256) shfL[tid] = sh;
  }
  __syncthreads();

  for (int u = tid; u < 3072; u += 1024) {
    const int t = u >> 6, l = u & 63, r15 = l & 15, g4 = l >> 4;
    Pk8 pk;
    if (t < 16) {                                   // L1 combined 256x32 (+bias col 12)
      const int wm = t >> 2, tr = t & 3, row = 64*wm + 16*tr + r15;
#pragma unroll
      for (int j = 0; j < 8; ++j) {
        const int k = 8*g4 + j; float val = 0.f;
        if (wm == 0) { if (k >= 9 && k < 12) val = cw1[row*3 + (k-9)]; }
        else if (k < 9) {
          const int e = wm - 1, o = row - 64*wm, c = (k - 3*e + 9) % 9;
          if (c < 6) val = vw1[o*6 + c];
        }
        pk.h[j] = (k == 12) ? (f16)shfL[row] : (f16)(val * scsL[row]);
      }
    } else if (t < 24) {                            // c2
      const int tt = t-16, rt = tt >> 1, s = tt & 1, row = 16*rt + r15;
#pragma unroll
      for (int j = 0; j < 8; ++j) { const int k = 32*s + 8*g4 + j;
        pk.h[j] = (f16)(cw2[row*64 + k] * scsL[256+row]); }
    } else if (t < 32) {                            // v2 (x 1/3)
      const int tt = t-24, rt = tt >> 1, s = tt & 1, row = 16*rt + r15;
#pragma unroll
      for (int j = 0; j < 8; ++j) { const int k = 32*s + 8*g4 + j;
        pk.h[j] = (f16)(vw2[row*64 + k] * scsL[320+row]); }
    } else {                                        // s (64x128)
      const int tt = t-32, rt = tt >> 2, s = tt & 3, row = 16*rt + r15;
#pragma unroll
      for (int j = 0; j < 8; ++j) { const int k = 32*s + 8*g4 + j;
        pk.h[j] = (f16)(sw[row*128 + k] * scsL[384+row]); }
    }
    *(uint4*)(wsW + (size_t)t*512 + l*8) = pk.u;
  }
}

// ---------------- main: wave-autonomous, ONE barrier ----------------
// Each wave owns 32 cols. Per branch quarter: L1(4 row-tiles) -> private LDS ->
// L2(branch). Then cv/L3 in two K-half passes reusing the same 64-k buffer.
__global__ __launch_bounds__(512, 4) void sd_main(const int* __restrict__ faces,
    const float* __restrict__ verts, const float* __restrict__ centers,
    const f16* __restrict__ wsW, const float* __restrict__ shsG,
    float* __restrict__ out)
{
  __shared__ f16  Wl[32 * 512];        // 32 KB: L1 + c2 + v2 tiles
  __shared__ f16  Ab[WPB][32 * 72];    // 36 KB: per-wave act buffer [col][64k + swz pad]
  __shared__ float shsL[192];          // c2 | v2 | s shifts

  const int tid  = threadIdx.x;
  const int lane = tid & 63;
  const int r15  = lane & 15;
  const int g4   = lane >> 4;
  const int w    = __builtin_amdgcn_readfirstlane(tid >> 6);
  const int sw   = (r15 & 7) << 3;

  // ---- stage weights + shifts (the only barrier) ----
  {
    const uint4* src = (const uint4*)wsW;
    uint4* dst = (uint4*)Wl;
#pragma unroll
    for (int i = 0; i < 4; ++i) dst[tid + i*512] = src[tid + i*512];
  }
  if (tid < 192) shsL[tid] = shsG[256 + tid];

  // wave-tile: wt in [0,25000); by = wt/3125, f0 = (wt%3125)*32
  const int wt = blockIdx.x * WPB + w;
  const int by = wt / 3125;
  const int f0 = (wt - by * 3125) * 32;

  // ---- gather X into B-frag registers (lane-direct, no LDS) ----
  FragU xf[2];
#pragma unroll
  for (int c = 0; c < 2; ++c) {
    float vals[8] = {0.f,0.f,0.f,0.f,0.f,0.f,0.f,0.f};
    const int f = f0 + 16*c + r15;
    if (g4 == 0) {
      const size_t fb3 = ((size_t)by*FN_ + f)*3;
      const int i0 = faces[fb3], i1 = faces[fb3+1], i2 = faces[fb3+2];
      const float* q0 = verts + ((size_t)by*V_ + (size_t)i0)*3;
      const float* q1 = verts + ((size_t)by*V_ + (size_t)i1)*3;
      const float* q2 = verts + ((size_t)by*V_ + (size_t)i2)*3;
      vals[0]=q0[0]; vals[1]=q0[1]; vals[2]=q0[2];
      vals[3]=q1[0]; vals[4]=q1[1]; vals[5]=q1[2];
      vals[6]=q2[0]; vals[7]=q2[1];
    } else if (g4 == 1) {
      const size_t fb3 = ((size_t)by*FN_ + f)*3;
      const int i2 = faces[fb3+2];
      const float* q2 = verts + ((size_t)by*V_ + (size_t)i2)*3;
      vals[0]=q2[2];
      vals[1]=centers[((size_t)by*3+0)*FN_ + f];
      vals[2]=centers[((size_t)by*3+1)*FN_ + f];
      vals[3]=centers[((size_t)by*3+2)*FN_ + f];
      vals[4]=1.0f;                                  // bias channel k=12
    }
#pragma unroll
    for (int m = 0; m < 4; ++m) xf[c].u[m] = pack2(vals[2*m], vals[2*m+1]);
  }
  __syncthreads();

  f16* ab = &Ab[w][0];
  const f16x8 zerofrag = {};
  (void)zerofrag;

  float    vf[4][2][4];
  uint32_t cfp[4][2][2];

  // ================== branch quarters: br0=c1/c2, br1..3=edge/v2 ==================
#pragma unroll
  for (int br = 0; br < 4; ++br) {
    // ---- L1 quarter: 4 row-tiles x 2 col-frags ----
    f32x4 acc1[4][2];
#pragma unroll
    for (int t4 = 0; t4 < 4; ++t4) {
      const f16x8 a = *(const f16x8*)&Wl[(4*br + t4)*512 + lane*8];
#pragma unroll
      for (int c = 0; c < 2; ++c) {
        f32x4 z = {0.f,0.f,0.f,0.f};
        acc1[t4][c] = __builtin_amdgcn_mfma_f32_16x16x32_f16(a, xf[c].v, z, 0,0,0);
      }
    }
#pragma unroll
    for (int t4 = 0; t4 < 4; ++t4)
#pragma unroll
      for (int c = 0; c < 2; ++c) {
        uint2 pw;
        pw.x = pack_relu2(acc1[t4][c][0], acc1[t4][c][1]);
        pw.y = pack_relu2(acc1[t4][c][2], acc1[t4][c][3]);
        *(uint2*)&ab[(16*c + r15)*72 + ((16*t4 + 4*g4) ^ sw)] = pw;
      }

    // ---- L2 quarter (this wave's own writes; intra-wave DS order, no barrier) ----
    f16x8 b2[2][2];
#pragma unroll
    for (int c = 0; c < 2; ++c)
#pragma unroll
      for (int s = 0; s < 2; ++s)
        b2[c][s] = *(const f16x8*)&ab[(16*c + r15)*72 + ((32*s + 8*g4) ^ sw)];

    const int wb = br ? 24 : 16;
    const int shb = br ? 64 : 0;
#pragma unroll
    for (int rt = 0; rt < 4; ++rt) {
      const f16x8 a0 = *(const f16x8*)&Wl[(wb + 2*rt    )*512 + lane*8];
      const f16x8 a1 = *(const f16x8*)&Wl[(wb + 2*rt + 1)*512 + lane*8];
      const f32x4 shv = *(const f32x4*)&shsL[shb + rt*16 + 4*g4];
#pragma unroll
      for (int c = 0; c < 2; ++c) {
        f32x4 acc = __builtin_amdgcn_mfma_f32_16x16x32_f16(a0, b2[c][0], shv, 0,0,0);
        acc = __builtin_amdgcn_mfma_f32_16x16x32_f16(a1, b2[c][1], acc, 0,0,0);
        if (br == 0) {
          cfp[rt][c][0] = pack_relu2(acc[0], acc[1]);
          cfp[rt][c][1] = pack_relu2(acc[2], acc[3]);
        } else if (br == 1) {
#pragma unroll
          for (int j = 0; j < 4; ++j) vf[rt][c][j] = fmaxf(acc[j], 0.f);
        } else {
#pragma unroll
          for (int j = 0; j < 4; ++j) vf[rt][c][j] += fmaxf(acc[j], 0.f);
        }
      }
    }
  }

  // ================== L3 in two K-half passes over the same 64-k buffer ==================
  f32x4 acc3[4][2];
#pragma unroll
  for (int rt = 0; rt < 4; ++rt) {
    const f32x4 shv = *(const f32x4*)&shsL[128 + rt*16 + 4*g4];
    acc3[rt][0] = shv; acc3[rt][1] = shv;
  }

#pragma unroll
  for (int half = 0; half < 2; ++half) {
    // write this half's cv (cf for half0, vf for half1)
#pragma unroll
    for (int rt = 0; rt < 4; ++rt)
#pragma unroll
      for (int c = 0; c < 2; ++c) {
        uint2 pw;
        if (half == 0) { pw.x = cfp[rt][c][0]; pw.y = cfp[rt][c][1]; }
        else { pw.x = pack2(vf[rt][c][0], vf[rt][c][1]);
               pw.y = pack2(vf[rt][c][2], vf[rt][c][3]); }
        *(uint2*)&ab[(16*c + r15)*72 + ((16*rt + 4*g4) ^ sw)] = pw;
      }
    // consume: K-steps sg = 2*half + {0,1}
#pragma unroll
    for (int s = 0; s < 2; ++s) {
      f16x8 b[2];
#pragma unroll
      for (int c = 0; c < 2; ++c)
        b[c] = *(const f16x8*)&ab[(16*c + r15)*72 + ((32*s + 8*g4) ^ sw)];
#pragma unroll
      for (int rt = 0; rt < 4; ++rt) {
        const f16x8 aS = *(const f16x8*)(wsW + (size_t)(32 + 4*rt + 2*half + s)*512 + lane*8);
        acc3[rt][0] = __builtin_amdgcn_mfma_f32_16x16x32_f16(aS, b[0], acc3[rt][0], 0,0,0);
        acc3[rt][1] = __builtin_amdgcn_mfma_f32_16x16x32_f16(aS, b[1], acc3[rt][1], 0,0,0);
      }
    }
  }

  // ---- stores ----
#pragma unroll
  for (int rt = 0; rt < 4; ++rt)
#pragma unroll
    for (int c = 0; c < 2; ++c) {
      const size_t base = ((size_t)(by*64 + rt*16 + 4*g4))*FN_ + (size_t)(f0 + 16*c + r15);
#pragma unroll
      for (int j = 0; j < 4; ++j)
        out[base + (size_t)j*FN_] = fmaxf(acc3[rt][c][j], 0.f);
    }
}

extern "C" void kernel_launch(void* const* d_in, const int* in_sizes, int n_in,
                              void* d_out, int out_size, void* d_ws, size_t ws_size,
                              hipStream_t stream) {
  (void)in_sizes; (void)n_in; (void)out_size; (void)ws_size;
  Ptrs p;
  for (int i = 0; i < 33; ++i) p.p[i] = d_in[i];
  f16*   wsW  = (f16*)d_ws;
  float* shsG = (float*)((char*)d_ws + WS_SHS);
  hipLaunchKernelGGL(sd_prep, dim3(1), dim3(1024), 0, stream, p, wsW, shsG);
  hipLaunchKernelGGL(sd_main, dim3(NBLK), dim3(512), 0, stream,
                     (const int*)d_in[2], (const float*)d_in[1], (const float*)d_in[0],
                     wsW, shsG, (float*)d_out);
}

// Round 10
// 89.054 us; speedup vs baseline: 1.8061x; 1.4370x over previous
//
#include <hip/hip_runtime.h>
#include <cstddef>
#include <cstdint>

#define FN_ 100000
#define V_  50000
#define B_  8
// 100000 = 3125 * 32 -> each wave owns exactly 32 columns, no partial tiles.
#define WPB   8                     // waves per block (512 threads)
#define NBLK  3125                  // 25000 wave-tiles / 8

// d_ws layout (bytes): 48 weight tiles of 1 KB (fragment order), then shs f32[448]
//   tiles  0..15 : combined L1 (256x32): rows 0-63 c1, 64-127 e0, 128-191 e1, 192-255 e2
//                  k==12 column holds the folded BN SHIFT (bias-as-weight; X[12]=1)
//   tiles 16..23 : c2 (64x64)
//   tiles 24..31 : v2 (64x64, x1/3 folded)
//   tiles 32..47 : s  (64x128)   (read from global; L2-resident)
#define WS_SHS 49152

typedef _Float16 f16;
typedef f16   f16x8 __attribute__((ext_vector_type(8)));
typedef float f32x4 __attribute__((ext_vector_type(4)));

struct Ptrs { const void* p[33]; };

union Pk8 { f16 h[8]; uint4 u; };
union FragU { uint32_t u[4]; f16x8 v; };

__device__ __forceinline__ uint32_t pack2(float a, float b) {
  return __builtin_bit_cast(uint32_t, __builtin_amdgcn_cvt_pkrtz(a, b));
}
__device__ __forceinline__ uint32_t pack_relu2(float a, float b) {
  uint32_t r, x = pack2(a, b);
  asm("v_pk_max_f16 %0, %1, 0" : "=v"(r) : "v"(x));
  return r;
}

// ---------------- prep: fold BN into f16 weights, fragment-ordered ----------------
__global__ __launch_bounds__(1024) void sd_prep(Ptrs in, f16* __restrict__ wsW,
                                                float* __restrict__ shsG)
{
  const float* __restrict__ cw1 = (const float*)in.p[3];
  const float* __restrict__ cb1 = (const float*)in.p[4];
  const float* __restrict__ c1g = (const float*)in.p[5];
  const float* __restrict__ c1bt= (const float*)in.p[6];
  const float* __restrict__ c1m = (const float*)in.p[7];
  const float* __restrict__ c1v = (const float*)in.p[8];
  const float* __restrict__ cw2 = (const float*)in.p[9];
  const float* __restrict__ cb2 = (const float*)in.p[10];
  const float* __restrict__ c2g = (const float*)in.p[11];
  const float* __restrict__ c2bt= (const float*)in.p[12];
  const float* __restrict__ c2m = (const float*)in.p[13];
  const float* __restrict__ c2v = (const float*)in.p[14];
  const float* __restrict__ vw1 = (const float*)in.p[15];
  const float* __restrict__ vb1 = (const float*)in.p[16];
  const float* __restrict__ v1g = (const float*)in.p[17];
  const float* __restrict__ v1bt= (const float*)in.p[18];
  const float* __restrict__ v1m = (const float*)in.p[19];
  const float* __restrict__ v1v = (const float*)in.p[20];
  const float* __restrict__ vw2 = (const float*)in.p[21];
  const float* __restrict__ vb2 = (const float*)in.p[22];
  const float* __restrict__ v2g = (const float*)in.p[23];
  const float* __restrict__ v2bt= (const float*)in.p[24];
  const float* __restrict__ v2m = (const float*)in.p[25];
  const float* __restrict__ v2v = (const float*)in.p[26];
  const float* __restrict__ sw  = (const float*)in.p[27];
  const float* __restrict__ sb  = (const float*)in.p[28];
  const float* __restrict__ s1g = (const float*)in.p[29];
  const float* __restrict__ s1bt= (const float*)in.p[30];
  const float* __restrict__ s1m = (const float*)in.p[31];
  const float* __restrict__ s1v = (const float*)in.p[32];

  __shared__ float scsL[448];
  __shared__ float shfL[256];       // L1 shifts for the bias-column trick
  const int tid = threadIdx.x;

  if (tid < 448) {
    const float *g, *v, *bb, *m, *bt; int o; float mul = 1.f;
    if (tid < 64)       { o = tid;      g=c1g; v=c1v; bb=cb1; m=c1m; bt=c1bt; }
    else if (tid < 256) { o = tid & 63; g=v1g; v=v1v; bb=vb1; m=v1m; bt=v1bt; }
    else if (tid < 320) { o = tid-256;  g=c2g; v=c2v; bb=cb2; m=c2m; bt=c2bt; }
    else if (tid < 384) { o = tid-320;  g=v2g; v=v2v; bb=vb2; m=v2m; bt=v2bt; mul = 1.f/3.f; }
    else                { o = tid-384;  g=s1g; v=s1v; bb=sb;  m=s1m; bt=s1bt; }
    float s = g[o] * rsqrtf(v[o] + 1e-5f);
    float sh = ((bb[o] - m[o]) * s + bt[o]) * mul;
    scsL[tid] = s * mul;
    shsG[tid] = sh;
    if (tid < 256) shfL[tid] = sh;
  }
  __syncthreads();

  for (int u = tid; u < 3072; u += 1024) {
    const int t = u >> 6, l = u & 63, r15 = l & 15, g4 = l >> 4;
    Pk8 pk;
    if (t < 16) {                                   // L1 combined 256x32 (+bias col 12)
      const int wm = t >> 2, tr = t & 3, row = 64*wm + 16*tr + r15;
#pragma unroll
      for (int j = 0; j < 8; ++j) {
        const int k = 8*g4 + j; float val = 0.f;
        if (wm == 0) { if (k >= 9 && k < 12) val = cw1[row*3 + (k-9)]; }
        else if (k < 9) {
          const int e = wm - 1, o = row - 64*wm, c = (k - 3*e + 9) % 9;
          if (c < 6) val = vw1[o*6 + c];
        }
        pk.h[j] = (k == 12) ? (f16)shfL[row] : (f16)(val * scsL[row]);
      }
    } else if (t < 24) {                            // c2
      const int tt = t-16, rt = tt >> 1, s = tt & 1, row = 16*rt + r15;
#pragma unroll
      for (int j = 0; j < 8; ++j) { const int k = 32*s + 8*g4 + j;
        pk.h[j] = (f16)(cw2[row*64 + k] * scsL[256+row]); }
    } else if (t < 32) {                            // v2 (x 1/3)
      const int tt = t-24, rt = tt >> 1, s = tt & 1, row = 16*rt + r15;
#pragma unroll
      for (int j = 0; j < 8; ++j) { const int k = 32*s + 8*g4 + j;
        pk.h[j] = (f16)(vw2[row*64 + k] * scsL[320+row]); }
    } else {                                        // s (64x128)
      const int tt = t-32, rt = tt >> 2, s = tt & 3, row = 16*rt + r15;
#pragma unroll
      for (int j = 0; j < 8; ++j) { const int k = 32*s + 8*g4 + j;
        pk.h[j] = (f16)(sw[row*128 + k] * scsL[384+row]); }
    }
    *(uint4*)(wsW + (size_t)t*512 + l*8) = pk.u;
  }
}

// ---------------- main: wave-autonomous, ONE barrier ----------------
// Act buffer: stride EXACTLY 64 f16 (128 B, ≡0 mod 32 banks) + XOR swizzle
// k ^ ((col&7)<<3): per quarter-wave every b128 read hits 8 distinct 16B
// window positions -> conflict-free by construction (R9's +8 pad broke this:
// 36dw stride made all addresses ≡0 mod 4dw -> 8 banks -> 8-way conflicts).
__global__ __launch_bounds__(512, 4) void sd_main(const int* __restrict__ faces,
    const float* __restrict__ verts, const float* __restrict__ centers,
    const f16* __restrict__ wsW, const float* __restrict__ shsG,
    float* __restrict__ out)
{
  __shared__ f16  Wl[32 * 512];        // 32 KB: L1 + c2 + v2 tiles
  __shared__ f16  Ab[WPB][32 * 64];    // 32 KB: per-wave act buffer, stride 64, swizzled
  __shared__ float shsL[192];          // c2 | v2 | s shifts

  const int tid  = threadIdx.x;
  const int lane = tid & 63;
  const int r15  = lane & 15;
  const int g4   = lane >> 4;
  const int w    = __builtin_amdgcn_readfirstlane(tid >> 6);
  const int sw   = (r15 & 7) << 3;

  // ---- stage weights + shifts (the only barrier) ----
  {
    const uint4* src = (const uint4*)wsW;
    uint4* dst = (uint4*)Wl;
#pragma unroll
    for (int i = 0; i < 4; ++i) dst[tid + i*512] = src[tid + i*512];
  }
  if (tid < 192) shsL[tid] = shsG[256 + tid];

  // wave-tile: wt in [0,25000); by = wt/3125, f0 = (wt%3125)*32
  const int wt = blockIdx.x * WPB + w;
  const int by = wt / 3125;
  const int f0 = (wt - by * 3125) * 32;

  // ---- gather X into B-frag registers (lane-direct, no LDS) ----
  FragU xf[2];
#pragma unroll
  for (int c = 0; c < 2; ++c) {
    float vals[8] = {0.f,0.f,0.f,0.f,0.f,0.f,0.f,0.f};
    const int f = f0 + 16*c + r15;
    if (g4 == 0) {
      const size_t fb3 = ((size_t)by*FN_ + f)*3;
      const int i0 = faces[fb3], i1 = faces[fb3+1], i2 = faces[fb3+2];
      const float* q0 = verts + ((size_t)by*V_ + (size_t)i0)*3;
      const float* q1 = verts + ((size_t)by*V_ + (size_t)i1)*3;
      const float* q2 = verts + ((size_t)by*V_ + (size_t)i2)*3;
      vals[0]=q0[0]; vals[1]=q0[1]; vals[2]=q0[2];
      vals[3]=q1[0]; vals[4]=q1[1]; vals[5]=q1[2];
      vals[6]=q2[0]; vals[7]=q2[1];
    } else if (g4 == 1) {
      const size_t fb3 = ((size_t)by*FN_ + f)*3;
      const int i2 = faces[fb3+2];
      const float* q2 = verts + ((size_t)by*V_ + (size_t)i2)*3;
      vals[0]=q2[2];
      vals[1]=centers[((size_t)by*3+0)*FN_ + f];
      vals[2]=centers[((size_t)by*3+1)*FN_ + f];
      vals[3]=centers[((size_t)by*3+2)*FN_ + f];
      vals[4]=1.0f;                                  // bias channel k=12
    }
#pragma unroll
    for (int m = 0; m < 4; ++m) xf[c].u[m] = pack2(vals[2*m], vals[2*m+1]);
  }
  __syncthreads();

  f16* ab = &Ab[w][0];

  float    vf[4][2][4];
  uint32_t cfp[4][2][2];

  // ================== branch quarters: br0=c1/c2, br1..3=edge/v2 ==================
#pragma unroll
  for (int br = 0; br < 4; ++br) {
    // ---- L1 quarter: 4 row-tiles x 2 col-frags ----
    f32x4 acc1[4][2];
#pragma unroll
    for (int t4 = 0; t4 < 4; ++t4) {
      const f16x8 a = *(const f16x8*)&Wl[(4*br + t4)*512 + lane*8];
#pragma unroll
      for (int c = 0; c < 2; ++c) {
        f32x4 z = {0.f,0.f,0.f,0.f};
        acc1[t4][c] = __builtin_amdgcn_mfma_f32_16x16x32_f16(a, xf[c].v, z, 0,0,0);
      }
    }
#pragma unroll
    for (int t4 = 0; t4 < 4; ++t4)
#pragma unroll
      for (int c = 0; c < 2; ++c) {
        uint2 pw;
        pw.x = pack_relu2(acc1[t4][c][0], acc1[t4][c][1]);
        pw.y = pack_relu2(acc1[t4][c][2], acc1[t4][c][3]);
        *(uint2*)&ab[(16*c + r15)*64 + ((16*t4 + 4*g4) ^ sw)] = pw;
      }

    // ---- L2 quarter (this wave's own writes; intra-wave DS order, no barrier) ----
    f16x8 b2[2][2];
#pragma unroll
    for (int c = 0; c < 2; ++c)
#pragma unroll
      for (int s = 0; s < 2; ++s)
        b2[c][s] = *(const f16x8*)&ab[(16*c + r15)*64 + ((32*s + 8*g4) ^ sw)];

    const int wb = br ? 24 : 16;
    const int shb = br ? 64 : 0;
#pragma unroll
    for (int rt = 0; rt < 4; ++rt) {
      const f16x8 a0 = *(const f16x8*)&Wl[(wb + 2*rt    )*512 + lane*8];
      const f16x8 a1 = *(const f16x8*)&Wl[(wb + 2*rt + 1)*512 + lane*8];
      const f32x4 shv = *(const f32x4*)&shsL[shb + rt*16 + 4*g4];
#pragma unroll
      for (int c = 0; c < 2; ++c) {
        f32x4 acc = __builtin_amdgcn_mfma_f32_16x16x32_f16(a0, b2[c][0], shv, 0,0,0);
        acc = __builtin_amdgcn_mfma_f32_16x16x32_f16(a1, b2[c][1], acc, 0,0,0);
        if (br == 0) {
          cfp[rt][c][0] = pack_relu2(acc[0], acc[1]);
          cfp[rt][c][1] = pack_relu2(acc[2], acc[3]);
        } else if (br == 1) {
#pragma unroll
          for (int j = 0; j < 4; ++j) vf[rt][c][j] = fmaxf(acc[j], 0.f);
        } else {
#pragma unroll
          for (int j = 0; j < 4; ++j) vf[rt][c][j] += fmaxf(acc[j], 0.f);
        }
      }
    }
  }

  // ================== L3 in two K-half passes over the same 64-k buffer ==================
  f32x4 acc3[4][2];
#pragma unroll
  for (int rt = 0; rt < 4; ++rt) {
    const f32x4 shv = *(const f32x4*)&shsL[128 + rt*16 + 4*g4];
    acc3[rt][0] = shv; acc3[rt][1] = shv;
  }

#pragma unroll
  for (int half = 0; half < 2; ++half) {
    // write this half's cv (cf for half0, vf for half1)
#pragma unroll
    for (int rt = 0; rt < 4; ++rt)
#pragma unroll
      for (int c = 0; c < 2; ++c) {
        uint2 pw;
        if (half == 0) { pw.x = cfp[rt][c][0]; pw.y = cfp[rt][c][1]; }
        else { pw.x = pack2(vf[rt][c][0], vf[rt][c][1]);
               pw.y = pack2(vf[rt][c][2], vf[rt][c][3]); }
        *(uint2*)&ab[(16*c + r15)*64 + ((16*rt + 4*g4) ^ sw)] = pw;
      }
    // consume: K-steps sg = 2*half + {0,1}
#pragma unroll
    for (int s = 0; s < 2; ++s) {
      f16x8 b[2];
#pragma unroll
      for (int c = 0; c < 2; ++c)
        b[c] = *(const f16x8*)&ab[(16*c + r15)*64 + ((32*s + 8*g4) ^ sw)];
#pragma unroll
      for (int rt = 0; rt < 4; ++rt) {
        const f16x8 aS = *(const f16x8*)(wsW + (size_t)(32 + 4*rt + 2*half + s)*512 + lane*8);
        acc3[rt][0] = __builtin_amdgcn_mfma_f32_16x16x32_f16(aS, b[0], acc3[rt][0], 0,0,0);
        acc3[rt][1] = __builtin_amdgcn_mfma_f32_16x16x32_f16(aS, b[1], acc3[rt][1], 0,0,0);
      }
    }
  }

  // ---- stores ----
#pragma unroll
  for (int rt = 0; rt < 4; ++rt)
#pragma unroll
    for (int c = 0; c < 2; ++c) {
      const size_t base = ((size_t)(by*64 + rt*16 + 4*g4))*FN_ + (size_t)(f0 + 16*c + r15);
#pragma unroll
      for (int j = 0; j < 4; ++j)
        out[base + (size_t)j*FN_] = fmaxf(acc3[rt][c][j], 0.f);
    }
}

extern "C" void kernel_launch(void* const* d_in, const int* in_sizes, int n_in,
                              void* d_out, int out_size, void* d_ws, size_t ws_size,
                              hipStream_t stream) {
  (void)in_sizes; (void)n_in; (void)out_size; (void)ws_size;
  Ptrs p;
  for (int i = 0; i < 33; ++i) p.p[i] = d_in[i];
  f16*   wsW  = (f16*)d_ws;
  float* shsG = (float*)((char*)d_ws + WS_SHS);
  hipLaunchKernelGGL(sd_prep, dim3(1), dim3(1024), 0, stream, p, wsW, shsG);
  hipLaunchKernelGGL(sd_main, dim3(NBLK), dim3(512), 0, stream,
                     (const int*)d_in[2], (const float*)d_in[1], (const float*)d_in[0],
                     wsW, shsG, (float*)d_out);
}

// Round 11
// 86.480 us; speedup vs baseline: 1.8598x; 1.0298x over previous
//
#include <hip/hip_runtime.h>
#include <cstddef>
#include <cstdint>

#define FN_ 100000
#define V_  50000
#define B_  8
// 100000 = 3125 * 32 -> each wave owns exactly 32 columns, no partial tiles.
#define WPB   8                     // waves per block (512 threads)
#define NBLK  3125                  // 25000 wave-tiles / 8

// d_ws layout (bytes): 48 weight tiles of 1 KB (fragment order), then shs f32[448]
//   tiles  0..15 : combined L1 (256x32): rows 0-63 c1, 64-127 e0, 128-191 e1, 192-255 e2
//                  k==12 column holds the folded BN SHIFT (bias-as-weight; X[12]=1)
//   tiles 16..23 : c2 (64x64)
//   tiles 24..31 : v2 (64x64, x1/3 folded)
//   tiles 32..47 : s  (64x128)   (prefetched to REGISTERS per wave)
#define WS_SHS 49152

typedef _Float16 f16;
typedef f16   f16x8 __attribute__((ext_vector_type(8)));
typedef float f32x4 __attribute__((ext_vector_type(4)));

struct Ptrs { const void* p[33]; };

union Pk8 { f16 h[8]; uint4 u; };
union FragU { uint32_t u[4]; f16x8 v; };

__device__ __forceinline__ uint32_t pack2(float a, float b) {
  return __builtin_bit_cast(uint32_t, __builtin_amdgcn_cvt_pkrtz(a, b));
}
__device__ __forceinline__ uint32_t pack_relu2(float a, float b) {
  uint32_t r, x = pack2(a, b);
  asm("v_pk_max_f16 %0, %1, 0" : "=v"(r) : "v"(x));
  return r;
}

// ---------------- prep: fold BN into f16 weights, fragment-ordered ----------------
__global__ __launch_bounds__(1024) void sd_prep(Ptrs in, f16* __restrict__ wsW,
                                                float* __restrict__ shsG)
{
  const float* __restrict__ cw1 = (const float*)in.p[3];
  const float* __restrict__ cb1 = (const float*)in.p[4];
  const float* __restrict__ c1g = (const float*)in.p[5];
  const float* __restrict__ c1bt= (const float*)in.p[6];
  const float* __restrict__ c1m = (const float*)in.p[7];
  const float* __restrict__ c1v = (const float*)in.p[8];
  const float* __restrict__ cw2 = (const float*)in.p[9];
  const float* __restrict__ cb2 = (const float*)in.p[10];
  const float* __restrict__ c2g = (const float*)in.p[11];
  const float* __restrict__ c2bt= (const float*)in.p[12];
  const float* __restrict__ c2m = (const float*)in.p[13];
  const float* __restrict__ c2v = (const float*)in.p[14];
  const float* __restrict__ vw1 = (const float*)in.p[15];
  const float* __restrict__ vb1 = (const float*)in.p[16];
  const float* __restrict__ v1g = (const float*)in.p[17];
  const float* __restrict__ v1bt= (const float*)in.p[18];
  const float* __restrict__ v1m = (const float*)in.p[19];
  const float* __restrict__ v1v = (const float*)in.p[20];
  const float* __restrict__ vw2 = (const float*)in.p[21];
  const float* __restrict__ vb2 = (const float*)in.p[22];
  const float* __restrict__ v2g = (const float*)in.p[23];
  const float* __restrict__ v2bt= (const float*)in.p[24];
  const float* __restrict__ v2m = (const float*)in.p[25];
  const float* __restrict__ v2v = (const float*)in.p[26];
  const float* __restrict__ sw  = (const float*)in.p[27];
  const float* __restrict__ sb  = (const float*)in.p[28];
  const float* __restrict__ s1g = (const float*)in.p[29];
  const float* __restrict__ s1bt= (const float*)in.p[30];
  const float* __restrict__ s1m = (const float*)in.p[31];
  const float* __restrict__ s1v = (const float*)in.p[32];

  __shared__ float scsL[448];
  __shared__ float shfL[256];       // L1 shifts for the bias-column trick
  const int tid = threadIdx.x;

  if (tid < 448) {
    const float *g, *v, *bb, *m, *bt; int o; float mul = 1.f;
    if (tid < 64)       { o = tid;      g=c1g; v=c1v; bb=cb1; m=c1m; bt=c1bt; }
    else if (tid < 256) { o = tid & 63; g=v1g; v=v1v; bb=vb1; m=v1m; bt=v1bt; }
    else if (tid < 320) { o = tid-256;  g=c2g; v=c2v; bb=cb2; m=c2m; bt=c2bt; }
    else if (tid < 384) { o = tid-320;  g=v2g; v=v2v; bb=vb2; m=v2m; bt=v2bt; mul = 1.f/3.f; }
    else                { o = tid-384;  g=s1g; v=s1v; bb=sb;  m=s1m; bt=s1bt; }
    float s = g[o] * rsqrtf(v[o] + 1e-5f);
    float sh = ((bb[o] - m[o]) * s + bt[o]) * mul;
    scsL[tid] = s * mul;
    shsG[tid] = sh;
    if (tid < 256) shfL[tid] = sh;
  }
  __syncthreads();

  for (int u = tid; u < 3072; u += 1024) {
    const int t = u >> 6, l = u & 63, r15 = l & 15, g4 = l >> 4;
    Pk8 pk;
    if (t < 16) {                                   // L1 combined 256x32 (+bias col 12)
      const int wm = t >> 2, tr = t & 3, row = 64*wm + 16*tr + r15;
#pragma unroll
      for (int j = 0; j < 8; ++j) {
        const int k = 8*g4 + j; float val = 0.f;
        if (wm == 0) { if (k >= 9 && k < 12) val = cw1[row*3 + (k-9)]; }
        else if (k < 9) {
          const int e = wm - 1, o = row - 64*wm, c = (k - 3*e + 9) % 9;
          if (c < 6) val = vw1[o*6 + c];
        }
        pk.h[j] = (k == 12) ? (f16)shfL[row] : (f16)(val * scsL[row]);
      }
    } else if (t < 24) {                            // c2
      const int tt = t-16, rt = tt >> 1, s = tt & 1, row = 16*rt + r15;
#pragma unroll
      for (int j = 0; j < 8; ++j) { const int k = 32*s + 8*g4 + j;
        pk.h[j] = (f16)(cw2[row*64 + k] * scsL[256+row]); }
    } else if (t < 32) {                            // v2 (x 1/3)
      const int tt = t-24, rt = tt >> 1, s = tt & 1, row = 16*rt + r15;
#pragma unroll
      for (int j = 0; j < 8; ++j) { const int k = 32*s + 8*g4 + j;
        pk.h[j] = (f16)(vw2[row*64 + k] * scsL[320+row]); }
    } else {                                        // s (64x128)
      const int tt = t-32, rt = tt >> 2, s = tt & 3, row = 16*rt + r15;
#pragma unroll
      for (int j = 0; j < 8; ++j) { const int k = 32*s + 8*g4 + j;
        pk.h[j] = (f16)(sw[row*128 + k] * scsL[384+row]); }
    }
    *(uint4*)(wsW + (size_t)t*512 + l*8) = pk.u;
  }
}

// ---------------- main: wave-autonomous, ONE barrier ----------------
// R10 + one change: the 16 s-weight fragments are prefetched into REGISTERS
// right after the barrier (they were per-use global loads inside L3's
// dependent chain -> serial vmcnt stalls at the end of the pipeline).
// +64 VGPR -> ~124, still 4 waves/SIMD at launch_bounds(512,4).
__global__ __launch_bounds__(512, 4) void sd_main(const int* __restrict__ faces,
    const float* __restrict__ verts, const float* __restrict__ centers,
    const f16* __restrict__ wsW, const float* __restrict__ shsG,
    float* __restrict__ out)
{
  __shared__ f16  Wl[32 * 512];        // 32 KB: L1 + c2 + v2 tiles
  __shared__ f16  Ab[WPB][32 * 64];    // 32 KB: per-wave act buffer, stride 64, swizzled
  __shared__ float shsL[192];          // c2 | v2 | s shifts

  const int tid  = threadIdx.x;
  const int lane = tid & 63;
  const int r15  = lane & 15;
  const int g4   = lane >> 4;
  const int w    = __builtin_amdgcn_readfirstlane(tid >> 6);
  const int sw   = (r15 & 7) << 3;

  // ---- stage weights + shifts (the only barrier) ----
  {
    const uint4* src = (const uint4*)wsW;
    uint4* dst = (uint4*)Wl;
#pragma unroll
    for (int i = 0; i < 4; ++i) dst[tid + i*512] = src[tid + i*512];
  }
  if (tid < 192) shsL[tid] = shsG[256 + tid];

  // wave-tile: wt in [0,25000); by = wt/3125, f0 = (wt%3125)*32
  const int wt = blockIdx.x * WPB + w;
  const int by = wt / 3125;
  const int f0 = (wt - by * 3125) * 32;

  // ---- gather X into B-frag registers (lane-direct, no LDS) ----
  FragU xf[2];
#pragma unroll
  for (int c = 0; c < 2; ++c) {
    float vals[8] = {0.f,0.f,0.f,0.f,0.f,0.f,0.f,0.f};
    const int f = f0 + 16*c + r15;
    if (g4 == 0) {
      const size_t fb3 = ((size_t)by*FN_ + f)*3;
      const int i0 = faces[fb3], i1 = faces[fb3+1], i2 = faces[fb3+2];
      const float* q0 = verts + ((size_t)by*V_ + (size_t)i0)*3;
      const float* q1 = verts + ((size_t)by*V_ + (size_t)i1)*3;
      const float* q2 = verts + ((size_t)by*V_ + (size_t)i2)*3;
      vals[0]=q0[0]; vals[1]=q0[1]; vals[2]=q0[2];
      vals[3]=q1[0]; vals[4]=q1[1]; vals[5]=q1[2];
      vals[6]=q2[0]; vals[7]=q2[1];
    } else if (g4 == 1) {
      const size_t fb3 = ((size_t)by*FN_ + f)*3;
      const int i2 = faces[fb3+2];
      const float* q2 = verts + ((size_t)by*V_ + (size_t)i2)*3;
      vals[0]=q2[2];
      vals[1]=centers[((size_t)by*3+0)*FN_ + f];
      vals[2]=centers[((size_t)by*3+1)*FN_ + f];
      vals[3]=centers[((size_t)by*3+2)*FN_ + f];
      vals[4]=1.0f;                                  // bias channel k=12
    }
#pragma unroll
    for (int m = 0; m < 4; ++m) xf[c].u[m] = pack2(vals[2*m], vals[2*m+1]);
  }
  __syncthreads();

  // ---- prefetch s-weight fragments (L2-hot) into registers; loads overlap
  //      the whole L1/L2 phase instead of stalling L3's chain ----
  f16x8 sfr[16];
#pragma unroll
  for (int i = 0; i < 16; ++i)
    sfr[i] = *(const f16x8*)(wsW + (size_t)(32 + i)*512 + lane*8);

  f16* ab = &Ab[w][0];

  float    vf[4][2][4];
  uint32_t cfp[4][2][2];

  // ================== branch quarters: br0=c1/c2, br1..3=edge/v2 ==================
#pragma unroll
  for (int br = 0; br < 4; ++br) {
    // ---- L1 quarter: 4 row-tiles x 2 col-frags ----
    f32x4 acc1[4][2];
#pragma unroll
    for (int t4 = 0; t4 < 4; ++t4) {
      const f16x8 a = *(const f16x8*)&Wl[(4*br + t4)*512 + lane*8];
#pragma unroll
      for (int c = 0; c < 2; ++c) {
        f32x4 z = {0.f,0.f,0.f,0.f};
        acc1[t4][c] = __builtin_amdgcn_mfma_f32_16x16x32_f16(a, xf[c].v, z, 0,0,0);
      }
    }
#pragma unroll
    for (int t4 = 0; t4 < 4; ++t4)
#pragma unroll
      for (int c = 0; c < 2; ++c) {
        uint2 pw;
        pw.x = pack_relu2(acc1[t4][c][0], acc1[t4][c][1]);
        pw.y = pack_relu2(acc1[t4][c][2], acc1[t4][c][3]);
        *(uint2*)&ab[(16*c + r15)*64 + ((16*t4 + 4*g4) ^ sw)] = pw;
      }

    // ---- L2 quarter (this wave's own writes; intra-wave DS order, no barrier) ----
    f16x8 b2[2][2];
#pragma unroll
    for (int c = 0; c < 2; ++c)
#pragma unroll
      for (int s = 0; s < 2; ++s)
        b2[c][s] = *(const f16x8*)&ab[(16*c + r15)*64 + ((32*s + 8*g4) ^ sw)];

    const int wb = br ? 24 : 16;
    const int shb = br ? 64 : 0;
#pragma unroll
    for (int rt = 0; rt < 4; ++rt) {
      const f16x8 a0 = *(const f16x8*)&Wl[(wb + 2*rt    )*512 + lane*8];
      const f16x8 a1 = *(const f16x8*)&Wl[(wb + 2*rt + 1)*512 + lane*8];
      const f32x4 shv = *(const f32x4*)&shsL[shb + rt*16 + 4*g4];
#pragma unroll
      for (int c = 0; c < 2; ++c) {
        f32x4 acc = __builtin_amdgcn_mfma_f32_16x16x32_f16(a0, b2[c][0], shv, 0,0,0);
        acc = __builtin_amdgcn_mfma_f32_16x16x32_f16(a1, b2[c][1], acc, 0,0,0);
        if (br == 0) {
          cfp[rt][c][0] = pack_relu2(acc[0], acc[1]);
          cfp[rt][c][1] = pack_relu2(acc[2], acc[3]);
        } else if (br == 1) {
#pragma unroll
          for (int j = 0; j < 4; ++j) vf[rt][c][j] = fmaxf(acc[j], 0.f);
        } else {
#pragma unroll
          for (int j = 0; j < 4; ++j) vf[rt][c][j] += fmaxf(acc[j], 0.f);
        }
      }
    }
  }

  // ================== L3 in two K-half passes over the same 64-k buffer ==================
  f32x4 acc3[4][2];
#pragma unroll
  for (int rt = 0; rt < 4; ++rt) {
    const f32x4 shv = *(const f32x4*)&shsL[128 + rt*16 + 4*g4];
    acc3[rt][0] = shv; acc3[rt][1] = shv;
  }

#pragma unroll
  for (int half = 0; half < 2; ++half) {
    // write this half's cv (cf for half0, vf for half1)
#pragma unroll
    for (int rt = 0; rt < 4; ++rt)
#pragma unroll
      for (int c = 0; c < 2; ++c) {
        uint2 pw;
        if (half == 0) { pw.x = cfp[rt][c][0]; pw.y = cfp[rt][c][1]; }
        else { pw.x = pack2(vf[rt][c][0], vf[rt][c][1]);
               pw.y = pack2(vf[rt][c][2], vf[rt][c][3]); }
        *(uint2*)&ab[(16*c + r15)*64 + ((16*rt + 4*g4) ^ sw)] = pw;
      }
    // consume: K-steps sg = 2*half + {0,1}
#pragma unroll
    for (int s = 0; s < 2; ++s) {
      f16x8 b[2];
#pragma unroll
      for (int c = 0; c < 2; ++c)
        b[c] = *(const f16x8*)&ab[(16*c + r15)*64 + ((32*s + 8*g4) ^ sw)];
#pragma unroll
      for (int rt = 0; rt < 4; ++rt) {
        const f16x8 aS = sfr[4*rt + 2*half + s];
        acc3[rt][0] = __builtin_amdgcn_mfma_f32_16x16x32_f16(aS, b[0], acc3[rt][0], 0,0,0);
        acc3[rt][1] = __builtin_amdgcn_mfma_f32_16x16x32_f16(aS, b[1], acc3[rt][1], 0,0,0);
      }
    }
  }

  // ---- stores ----
#pragma unroll
  for (int rt = 0; rt < 4; ++rt)
#pragma unroll
    for (int c = 0; c < 2; ++c) {
      const size_t base = ((size_t)(by*64 + rt*16 + 4*g4))*FN_ + (size_t)(f0 + 16*c + r15);
#pragma unroll
      for (int j = 0; j < 4; ++j)
        out[base + (size_t)j*FN_] = fmaxf(acc3[rt][c][j], 0.f);
    }
}

extern "C" void kernel_launch(void* const* d_in, const int* in_sizes, int n_in,
                              void* d_out, int out_size, void* d_ws, size_t ws_size,
                              hipStream_t stream) {
  (void)in_sizes; (void)n_in; (void)out_size; (void)ws_size;
  Ptrs p;
  for (int i = 0; i < 33; ++i) p.p[i] = d_in[i];
  f16*   wsW  = (f16*)d_ws;
  float* shsG = (float*)((char*)d_ws + WS_SHS);
  hipLaunchKernelGGL(sd_prep, dim3(1), dim3(1024), 0, stream, p, wsW, shsG);
  hipLaunchKernelGGL(sd_main, dim3(NBLK), dim3(512), 0, stream,
                     (const int*)d_in[2], (const float*)d_in[1], (const float*)d_in[0],
                     wsW, shsG, (float*)d_out);
}